// Round 1
// 2549.452 us; speedup vs baseline: 1.3028x; 1.3028x over previous
//
#include <hip/hip_runtime.h>

typedef __attribute__((ext_vector_type(4))) float f32x4;
typedef __attribute__((ext_vector_type(8))) short s16x8;
typedef __attribute__((ext_vector_type(8))) unsigned short u16x8;

#define TOKS_PER_B 50176   // 224*224
#define CDIM 384
#define OCDIM 1152

__device__ __forceinline__ unsigned short f2bf(float f) {
  unsigned u = __builtin_bit_cast(unsigned, f);
  u += 0x7FFFu + ((u >> 16) & 1u);
  return (unsigned short)(u >> 16);
}
__device__ __forceinline__ unsigned cvt_pk(float lo, float hi) {
  // packed f32->bf16 (RNE), lo -> D[15:0], hi -> D[31:16]
  unsigned r;
  asm("v_cvt_pk_bf16_f32 %0, %1, %2" : "=v"(r) : "v"(lo), "v"(hi));
  return r;
}

// ---------------- K1: qkv = x^T @ W^T + b, output bf16 [token][1152] ----------------
// 1D grid = 9 * (toks/128), XCD-swizzled so the 9 n-tiles of an m-tile share an XCD L2.
// block = 256 (4 waves), wave -> 64x64 subtile of the 128x128 tile.
// LDS: exact [128][32] bf16 tiles, XOR chunk swizzle -> all DS ops bank-conflict-free:
//   element (row, k) stored at chunk ((k>>3) ^ ((row ^ (row>>2)) & 3)), 8 bf16 per chunk.
__global__ __launch_bounds__(256) void qkv_gemm(
    const float* __restrict__ x, const float* __restrict__ wq,
    const float* __restrict__ bias, unsigned short* __restrict__ qkv,
    long long t_base, int nwg) {
  __shared__ unsigned short As[128][32];   // 8 KB
  __shared__ unsigned short Bs[128][32];   // 8 KB
  const int tid  = threadIdx.x;
  const int lane = tid & 63, wv = tid >> 6;

  // bijective XCD swizzle (m204): launched id -> contiguous wgid chunk per XCD
  const int qq  = nwg >> 3, rr = nwg & 7;
  const int xcd = blockIdx.x & 7, pos = blockIdx.x >> 3;
  const int wgid = (xcd < rr ? xcd * (qq + 1) : rr * (qq + 1) + (xcd - rr) * qq) + pos;
  const int nb = wgid % 9, mb = wgid / 9;   // n fastest: 9 blocks share one A-tile

  const long long t0 = t_base + (long long)mb * 128;
  const int b    = (int)(t0 / TOKS_PER_B);
  const int off0 = (int)(t0 - (long long)b * TOKS_PER_B);
  const float* xb = x + (size_t)b * CDIM * TOKS_PER_B + off0;
  const int n0 = nb * 128;
  const int ml = lane & 15, quad = lane >> 4;
  const int m_base = (wv & 1) * 64, n_base = (wv >> 1) * 64;

  // ---- A staging: thread -> 1 token, 16 k's (strided dword loads, coalesced over lanes)
  const int tok  = tid & 127;
  const int kh   = (tid >> 7) << 4;              // 0 or 16
  const int keyA = (tok ^ (tok >> 2)) & 3;
  const int cA0  = kh >> 3;                      // 0 or 2
  unsigned short* aw0 = &As[tok][((cA0 ^ keyA) << 3)];
  unsigned short* aw1 = &As[tok][(((cA0 + 1) ^ keyA) << 3)];
  const float* apk = xb + (size_t)kh * TOKS_PER_B + tok;

  // ---- B staging: thread -> oc rows bn+32p, k cols bk4..bk4+3 (float4 along k)
  const int bk4  = (tid & 7) * 4;
  const int bn   = tid >> 3;
  const int keyB = (bn ^ (bn >> 2)) & 3;         // rows bn+32p: same key
  const int bwoff = (((bk4 >> 3) ^ keyB) << 3) + (bk4 & 7);
  const float* wqp = wq + (size_t)(n0 + bn) * CDIM + bk4;

  // ---- fragment read swizzle (row = *+ml  ->  key depends on ml only)
  const int keyR = (ml ^ (ml >> 2)) & 3;
  const int rq   = (quad ^ keyR) << 3;

  f32x4 acc[4][4] = {};

  for (int ks = 0; ks < 12; ++ks) {
    float va[16];
    #pragma unroll
    for (int i = 0; i < 16; ++i) va[i] = apk[(size_t)i * TOKS_PER_B];
    float4 vb[4];
    #pragma unroll
    for (int p = 0; p < 4; ++p) vb[p] = *(const float4*)(wqp + (size_t)p * 32 * CDIM);

    uint4 w;
    w.x = cvt_pk(va[0], va[1]);   w.y = cvt_pk(va[2], va[3]);
    w.z = cvt_pk(va[4], va[5]);   w.w = cvt_pk(va[6], va[7]);
    *(uint4*)aw0 = w;
    w.x = cvt_pk(va[8], va[9]);   w.y = cvt_pk(va[10], va[11]);
    w.z = cvt_pk(va[12], va[13]); w.w = cvt_pk(va[14], va[15]);
    *(uint4*)aw1 = w;
    #pragma unroll
    for (int p = 0; p < 4; ++p) {
      uint2 u;
      u.x = cvt_pk(vb[p].x, vb[p].y);
      u.y = cvt_pk(vb[p].z, vb[p].w);
      *(uint2*)&Bs[bn + p * 32][bwoff] = u;
    }
    __syncthreads();

    s16x8 af[4], bf[4];
    #pragma unroll
    for (int mi = 0; mi < 4; ++mi)
      af[mi] = __builtin_bit_cast(s16x8, *(const u16x8*)&As[m_base + mi * 16 + ml][rq]);
    #pragma unroll
    for (int ni = 0; ni < 4; ++ni)
      bf[ni] = __builtin_bit_cast(s16x8, *(const u16x8*)&Bs[n_base + ni * 16 + ml][rq]);
    #pragma unroll
    for (int mi = 0; mi < 4; ++mi)
      #pragma unroll
      for (int ni = 0; ni < 4; ++ni)
        acc[mi][ni] = __builtin_amdgcn_mfma_f32_16x16x32_bf16(af[mi], bf[ni], acc[mi][ni], 0, 0, 0);
    __syncthreads();

    apk += (size_t)32 * TOKS_PER_B;
    wqp += 32;
  }

  const long long mrow0 = (long long)mb * 128 + m_base;   // chunk-local row
  #pragma unroll
  for (int ni = 0; ni < 4; ++ni) {
    const int col = n0 + n_base + ni * 16 + ml;   // C/D: col = lane&15
    const float bv = bias[col];
    #pragma unroll
    for (int mi = 0; mi < 4; ++mi) {
      #pragma unroll
      for (int r = 0; r < 4; ++r) {
        const long long mrow = mrow0 + mi * 16 + quad * 4 + r;  // row = quad*4+reg
        qkv[(size_t)mrow * OCDIM + col] = f2bf(acc[mi][ni][r] + bv);
      }
    }
  }
}

// ---------------- K2: per (window, head) attention, one wave per block ----------------
// grid = (windows_in_chunk, 4 heads), block = 64
__global__ __launch_bounds__(64) void win_attn(
    const unsigned short* __restrict__ qkv, float* __restrict__ out,
    int win_base) {
  __shared__ unsigned short sh[64 * 72 + 96 * 72];  // P[64][72] | Vt[96][72] ; 23040 B
  unsigned short* P  = sh;
  unsigned short* Vt = sh + 64 * 72;
  const int lane = threadIdx.x;
  const int win  = win_base + blockIdx.x;
  const int head = blockIdx.y;
  const int b = win >> 10, hw = (win >> 5) & 31, ww = win & 31;
  // local (chunk-relative) token of window pos (0,0); chunk token base = (win_base/32)*1568
  const long long t00 = (long long)b * TOKS_PER_B + (long long)hw * 7 * 224 + ww * 7
                        - (long long)(win_base >> 5) * 1568;
  const unsigned short* base = qkv + t00 * OCDIM + head * 96;
  const int ml = lane & 15, quad = lane >> 4;

  // stage V^T into LDS: Vt[d][j], zero-pad j=49..63
  for (int idx = lane; idx < 49 * 96; idx += 64) {
    const int pos = idx / 96, d = idx - pos * 96;
    const int r = pos / 7, cc = pos - r * 7;
    Vt[d * 72 + pos] = base[(size_t)(r * 224 + cc) * OCDIM + 768 + d];
  }
  for (int idx = lane; idx < 96 * 15; idx += 64) {
    const int d = idx / 15, j = 49 + (idx - d * 15);
    Vt[d * 72 + j] = 0;
  }

  // Q/K fragments straight from global (rows k-contiguous = operand layout)
  s16x8 aq[4][3], bk[4][3];
  const s16x8 zf = {0, 0, 0, 0, 0, 0, 0, 0};
  #pragma unroll
  for (int mi = 0; mi < 4; ++mi) {
    const int pos = mi * 16 + ml;
    if (pos < 49) {
      const int r = pos / 7, cc = pos - r * 7;
      const unsigned short* rowp = base + (size_t)(r * 224 + cc) * OCDIM;
      #pragma unroll
      for (int ks = 0; ks < 3; ++ks) {
        aq[mi][ks] = __builtin_bit_cast(s16x8, *(const u16x8*)(rowp + ks * 32 + quad * 8));
        bk[mi][ks] = __builtin_bit_cast(s16x8, *(const u16x8*)(rowp + 384 + ks * 32 + quad * 8));
      }
    } else {
      #pragma unroll
      for (int ks = 0; ks < 3; ++ks) { aq[mi][ks] = zf; bk[mi][ks] = zf; }
    }
  }

  // S = Q K^T  (64x64 padded; rows/cols >=49 are zeros)
  f32x4 sa[4][4] = {};
  #pragma unroll
  for (int ks = 0; ks < 3; ++ks)
    #pragma unroll
    for (int mi = 0; mi < 4; ++mi)
      #pragma unroll
      for (int ni = 0; ni < 4; ++ni)
        sa[mi][ni] = __builtin_amdgcn_mfma_f32_16x16x32_bf16(aq[mi][ks], bk[ni][ks], sa[mi][ni], 0, 0, 0);

  // softmax over rows of S (C/D layout: row = mi*16+quad*4+r spread over 16 lanes x 4 ni regs)
  const float scale = 0.10206207261596577f;  // 96^-0.5, folded into exp arg
  #pragma unroll
  for (int mi = 0; mi < 4; ++mi) {
    #pragma unroll
    for (int r = 0; r < 4; ++r) {
      float mx = -3.0e38f;
      #pragma unroll
      for (int ni = 0; ni < 4; ++ni)
        if (ni * 16 + ml < 49) mx = fmaxf(mx, sa[mi][ni][r]);
      mx = fmaxf(mx, __shfl_xor(mx, 1, 16));
      mx = fmaxf(mx, __shfl_xor(mx, 2, 16));
      mx = fmaxf(mx, __shfl_xor(mx, 4, 16));
      mx = fmaxf(mx, __shfl_xor(mx, 8, 16));
      float e[4], sum = 0.f;
      #pragma unroll
      for (int ni = 0; ni < 4; ++ni) {
        e[ni] = (ni * 16 + ml < 49) ? __expf((sa[mi][ni][r] - mx) * scale) : 0.f;
        sum += e[ni];
      }
      sum += __shfl_xor(sum, 1, 16);
      sum += __shfl_xor(sum, 2, 16);
      sum += __shfl_xor(sum, 4, 16);
      sum += __shfl_xor(sum, 8, 16);
      const float inv = 1.0f / sum;
      const int row = mi * 16 + quad * 4 + r;
      #pragma unroll
      for (int ni = 0; ni < 4; ++ni)
        P[row * 72 + ni * 16 + ml] = f2bf(e[ni] * inv);   // A-operand layout for PV
    }
  }

  // O = P V   (A = P[64x64], B^T = Vt[96][64])
  f32x4 oa[4][6] = {};
  #pragma unroll
  for (int ks = 0; ks < 2; ++ks) {
    s16x8 ap[4], bv[6];
    #pragma unroll
    for (int mi = 0; mi < 4; ++mi)
      ap[mi] = __builtin_bit_cast(s16x8, *(const u16x8*)&P[(mi * 16 + ml) * 72 + ks * 32 + quad * 8]);
    #pragma unroll
    for (int ni = 0; ni < 6; ++ni)
      bv[ni] = __builtin_bit_cast(s16x8, *(const u16x8*)&Vt[(ni * 16 + ml) * 72 + ks * 32 + quad * 8]);
    #pragma unroll
    for (int mi = 0; mi < 4; ++mi)
      #pragma unroll
      for (int ni = 0; ni < 6; ++ni)
        oa[mi][ni] = __builtin_amdgcn_mfma_f32_16x16x32_bf16(ap[mi], bv[ni], oa[mi][ni], 0, 0, 0);
  }

  // restage O through LDS (fp32 [49][99]) for channel-major coalesced-ish stores.
  // Safe without barrier: single wave; LDS ops execute in order; O stores depend on MFMA
  // results which depend on the P/Vt reads.
  float* O = (float*)sh;
  #pragma unroll
  for (int mi = 0; mi < 4; ++mi)
    #pragma unroll
    for (int r = 0; r < 4; ++r) {
      const int row = mi * 16 + quad * 4 + r;
      if (row < 49) {
        #pragma unroll
        for (int ni = 0; ni < 6; ++ni)
          O[row * 99 + ni * 16 + ml] = oa[mi][ni][r];
      }
    }
  const size_t obase = ((size_t)(b * CDIM + head * 96) * 224 + (size_t)hw * 7) * 224 + ww * 7;
  for (int idx = lane; idx < 49 * 96; idx += 64) {
    const int d = idx / 49, pos = idx - d * 49;
    const int r = pos / 7, cc = pos - r * 7;
    out[obase + ((size_t)d * 224 + r) * 224 + cc] = O[pos * 99 + d];
  }
}

extern "C" void kernel_launch(void* const* d_in, const int* in_sizes, int n_in,
                              void* d_out, int out_size, void* d_ws, size_t ws_size,
                              hipStream_t stream) {
  const float* x    = (const float*)d_in[0];
  const float* wq   = (const float*)d_in[1];
  const float* bias = (const float*)d_in[2];
  float* out = (float*)d_out;
  unsigned short* ws = (unsigned short*)d_ws;

  // chunk = multiple of 4 window-rows (6272 tokens = 49 M-tiles = 128 windows, 14.45 MB bf16 qkv)
  const long long UNIT_TOK = 6272;
  const size_t UNIT_BYTES = (size_t)UNIT_TOK * OCDIM * 2;
  int upc = (int)(ws_size / UNIT_BYTES);
  if (upc < 1) upc = 1;
  if (upc > 64) upc = 64;

  for (int u0 = 0; u0 < 64; u0 += upc) {
    const int units = (u0 + upc <= 64) ? upc : (64 - u0);
    const long long t_base = (long long)u0 * UNIT_TOK;
    const int toks = units * (int)UNIT_TOK;
    const int nwg = 9 * (toks / 128);
    qkv_gemm<<<dim3(nwg), dim3(256), 0, stream>>>(x, wq, bias, ws, t_base, nwg);
    dim3 g2(units * 128, 4);
    win_attn<<<g2, dim3(64), 0, stream>>>(ws, out, u0 * 128);
  }
}